// Round 6
// baseline (333.083 us; speedup 1.0000x reference)
//
#include <hip/hip_runtime.h>

#define N_NODES 50000
#define N_EDGES 1600000
#define N_HEAD 4
#define F_OUT 128
#define CAP 96        // per-node bucket capacity; Poisson(32), P(>96) ~ 5e-14
#define NPS 512       // nodes per super-bucket
#define K1 98         // ceil(50000/512)
#define SCAP 17408    // super capacity: mean 16327 + ~8.5 sigma
#define NPG 16        // nodes per agg block
#define GROUPS 3125   // 50000/16
#define EPB 2048      // edges per partition block
#define P1_BLOCKS ((N_EDGES + EPB - 1) / EPB)   // 782

// ---------------- K1: per-node scores + gc zeroing --------------------------------
__global__ void __launch_bounds__(256) score_kernel(
    const float* __restrict__ x, const float* __restrict__ w,
    const float* __restrict__ a, float4* __restrict__ s_src4,
    float4* __restrict__ s_dst4, int* __restrict__ gc) {
  if (blockIdx.x == 0 && threadIdx.x < K1) gc[threadIdx.x] = 0;
  int wv = (blockIdx.x * blockDim.x + threadIdx.x) >> 6;
  int lane = threadIdx.x & 63;
  if (wv >= N_NODES) return;
  float xv0 = x[wv * F_OUT + lane];
  float xv1 = x[wv * F_OUT + 64 + lane];
  float ps[N_HEAD], pd[N_HEAD];
#pragma unroll
  for (int h = 0; h < N_HEAD; ++h) {
    float w0 = w[h * F_OUT + lane];
    float w1 = w[h * F_OUT + 64 + lane];
    float as0 = a[h * 2 * F_OUT + lane];
    float as1 = a[h * 2 * F_OUT + 64 + lane];
    float ad0 = a[h * 2 * F_OUT + F_OUT + lane];
    float ad1 = a[h * 2 * F_OUT + F_OUT + 64 + lane];
    ps[h] = xv0 * w0 * as0 + xv1 * w1 * as1;
    pd[h] = xv0 * w0 * ad0 + xv1 * w1 * ad1;
  }
#pragma unroll
  for (int off = 32; off > 0; off >>= 1) {
#pragma unroll
    for (int h = 0; h < N_HEAD; ++h) {
      ps[h] += __shfl_xor(ps[h], off, 64);
      pd[h] += __shfl_xor(pd[h], off, 64);
    }
  }
  if (lane == 0) {
    s_src4[wv] = make_float4(ps[0], ps[1], ps[2], ps[3]);
    s_dst4[wv] = make_float4(pd[0], pd[1], pd[2], pd[3]);
  }
}

// ---------------- K2: block-local counting sort -> coalesced run writes ---------
__global__ void __launch_bounds__(256) partition_kernel(
    const int* __restrict__ src, const int* __restrict__ dst,
    int* __restrict__ gc, unsigned int* __restrict__ region) {
  __shared__ int hist[K1], cur[K1], lstart[K1], gpos[K1];
  __shared__ unsigned int staging[EPB];
  const int tid = threadIdx.x;
  const int base = blockIdx.x * EPB;
  int vc = N_EDGES - base;
  if (vc > EPB) vc = EPB;

  unsigned int pk[EPB / 256];
#pragma unroll
  for (int k = 0; k < EPB / 256; ++k) {
    int i = k * 256 + tid;
    if (i < vc) {
      unsigned int s = (unsigned int)src[base + i];
      unsigned int d = (unsigned int)dst[base + i];
      pk[k] = (s << 16) | d;
    } else {
      pk[k] = 0xffffffffu;
    }
  }
  if (tid < K1) { hist[tid] = 0; cur[tid] = 0; }
  __syncthreads();
#pragma unroll
  for (int k = 0; k < EPB / 256; ++k)
    if (pk[k] != 0xffffffffu) atomicAdd(&hist[pk[k] >> 25], 1);
  __syncthreads();
  if (tid < 64) {
    int carry = 0;
    for (int b0 = 0; b0 < K1; b0 += 64) {
      int idx = b0 + tid;
      int h = (idx < K1) ? hist[idx] : 0;
      int v = h;
#pragma unroll
      for (int off = 1; off < 64; off <<= 1) {
        int t = __shfl_up(v, off, 64);
        if (tid >= off) v += t;
      }
      if (idx < K1) {
        lstart[idx] = carry + v - h;
        gpos[idx] = atomicAdd(&gc[idx], h);
      }
      carry += __shfl(v, 63, 64);
    }
  }
  __syncthreads();
#pragma unroll
  for (int k = 0; k < EPB / 256; ++k) {
    if (pk[k] != 0xffffffffu) {
      int b = pk[k] >> 25;
      int pos = lstart[b] + atomicAdd(&cur[b], 1);
      staging[pos] = pk[k];
    }
  }
  __syncthreads();
  for (int i = tid; i < vc; i += 256) {
    unsigned int v = staging[i];
    int b = v >> 25;
    int off = gpos[b] + (i - lstart[b]);
    if (off < SCAP) region[(size_t)b * SCAP + off] = v;
  }
}

// ---------------- K3: fused LDS-bucket + gather/accumulate ----------------------
// One block per 16-node group. Phase B: half-wave per edge, float4 per lane ->
// one global_load_dwordx4 covers TWO x-rows; unroll x2 -> 4 rows in flight.
__global__ void __launch_bounds__(256, 8) agg_kernel(
    const float* __restrict__ x, const float* __restrict__ w,
    const float4* __restrict__ s_src4, const float4* __restrict__ s_dst4,
    const int* __restrict__ gc, const unsigned int* __restrict__ region,
    float* __restrict__ out) {
  __shared__ int ncnt[NPG];
  __shared__ int nbkt[NPG][CAP];
  __shared__ float4 lds_w[4][CAP];
  const int tid = threadIdx.x;
  const int g = blockIdx.x;
  const int sb = g >> 5;                 // 32 groups per super (512/16)
  int c = gc[sb];
  if (c > SCAP) c = SCAP;
  if (tid < NPG) ncnt[tid] = 0;
  __syncthreads();

  const unsigned int* reg = region + (size_t)sb * SCAP;
  const unsigned int gtag = (unsigned int)g;
  for (int i = tid; i < c; i += 256) {
    unsigned int v = reg[i];
    unsigned int s = v >> 16;
    if ((s >> 4) == gtag) {
      int l = s & 15;
      int p = atomicAdd(&ncnt[l], 1);
      if (p < CAP) nbkt[l][p] = (int)(v & 0xffffu);
    }
  }
  __syncthreads();

  const int ws = tid >> 6, lane = tid & 63;
  const int half = lane >> 5, fl = lane & 31;
  const float4* __restrict__ xq = (const float4*)x;
  const float4* __restrict__ wq = (const float4*)w;

  for (int l = ws; l < NPG; l += 4) {
    int n = g * NPG + l;
    if (n >= N_NODES) break;
    int m = ncnt[l];
    m = (m < CAP) ? m : CAP;
    float4 ss = s_src4[n];

    // ---- Phase A: weights into wave-private LDS, rowsums in registers ----
    float p0 = 0.f, p1 = 0.f, p2 = 0.f, p3 = 0.f;
    for (int j = lane; j < m; j += 64) {
      int d = nbkt[l][j];
      float4 sd = s_dst4[d];
      float sc0 = ss.x + sd.x, sc1 = ss.y + sd.y, sc2 = ss.z + sd.z, sc3 = ss.w + sd.w;
      float e0 = __expf(-fmaxf(sc0, 0.2f * sc0));
      float e1 = __expf(-fmaxf(sc1, 0.2f * sc1));
      float e2 = __expf(-fmaxf(sc2, 0.2f * sc2));
      float e3 = __expf(-fmaxf(sc3, 0.2f * sc3));
      lds_w[ws][j] = make_float4(e0, e1, e2, e3);
      p0 += e0; p1 += e1; p2 += e2; p3 += e3;
    }
#pragma unroll
    for (int off = 32; off > 0; off >>= 1) {
      p0 += __shfl_xor(p0, off, 64);
      p1 += __shfl_xor(p1, off, 64);
      p2 += __shfl_xor(p2, off, 64);
      p3 += __shfl_xor(p3, off, 64);
    }

    // ---- Phase B ----
    float4 A0 = {0, 0, 0, 0}, A1 = {0, 0, 0, 0}, A2 = {0, 0, 0, 0}, A3 = {0, 0, 0, 0};
    int j = 0;
    for (; j + 3 < m; j += 4) {
      int da = nbkt[l][j + half];
      int db = nbkt[l][j + 2 + half];
      float4 wa = lds_w[ws][j + half];
      float4 wb = lds_w[ws][j + 2 + half];
      float4 xa = xq[(size_t)da * 32 + fl];
      float4 xb = xq[(size_t)db * 32 + fl];
      A0.x = fmaf(wa.x, xa.x, A0.x); A0.y = fmaf(wa.x, xa.y, A0.y);
      A0.z = fmaf(wa.x, xa.z, A0.z); A0.w = fmaf(wa.x, xa.w, A0.w);
      A1.x = fmaf(wa.y, xa.x, A1.x); A1.y = fmaf(wa.y, xa.y, A1.y);
      A1.z = fmaf(wa.y, xa.z, A1.z); A1.w = fmaf(wa.y, xa.w, A1.w);
      A2.x = fmaf(wa.z, xa.x, A2.x); A2.y = fmaf(wa.z, xa.y, A2.y);
      A2.z = fmaf(wa.z, xa.z, A2.z); A2.w = fmaf(wa.z, xa.w, A2.w);
      A3.x = fmaf(wa.w, xa.x, A3.x); A3.y = fmaf(wa.w, xa.y, A3.y);
      A3.z = fmaf(wa.w, xa.z, A3.z); A3.w = fmaf(wa.w, xa.w, A3.w);
      A0.x = fmaf(wb.x, xb.x, A0.x); A0.y = fmaf(wb.x, xb.y, A0.y);
      A0.z = fmaf(wb.x, xb.z, A0.z); A0.w = fmaf(wb.x, xb.w, A0.w);
      A1.x = fmaf(wb.y, xb.x, A1.x); A1.y = fmaf(wb.y, xb.y, A1.y);
      A1.z = fmaf(wb.y, xb.z, A1.z); A1.w = fmaf(wb.y, xb.w, A1.w);
      A2.x = fmaf(wb.z, xb.x, A2.x); A2.y = fmaf(wb.z, xb.y, A2.y);
      A2.z = fmaf(wb.z, xb.z, A2.z); A2.w = fmaf(wb.z, xb.w, A2.w);
      A3.x = fmaf(wb.w, xb.x, A3.x); A3.y = fmaf(wb.w, xb.y, A3.y);
      A3.z = fmaf(wb.w, xb.z, A3.z); A3.w = fmaf(wb.w, xb.w, A3.w);
    }
    for (; j + 1 < m; j += 2) {
      int da = nbkt[l][j + half];
      float4 wa = lds_w[ws][j + half];
      float4 xa = xq[(size_t)da * 32 + fl];
      A0.x = fmaf(wa.x, xa.x, A0.x); A0.y = fmaf(wa.x, xa.y, A0.y);
      A0.z = fmaf(wa.x, xa.z, A0.z); A0.w = fmaf(wa.x, xa.w, A0.w);
      A1.x = fmaf(wa.y, xa.x, A1.x); A1.y = fmaf(wa.y, xa.y, A1.y);
      A1.z = fmaf(wa.y, xa.z, A1.z); A1.w = fmaf(wa.y, xa.w, A1.w);
      A2.x = fmaf(wa.z, xa.x, A2.x); A2.y = fmaf(wa.z, xa.y, A2.y);
      A2.z = fmaf(wa.z, xa.z, A2.z); A2.w = fmaf(wa.z, xa.w, A2.w);
      A3.x = fmaf(wa.w, xa.x, A3.x); A3.y = fmaf(wa.w, xa.y, A3.y);
      A3.z = fmaf(wa.w, xa.z, A3.z); A3.w = fmaf(wa.w, xa.w, A3.w);
    }
    if (j < m) {  // odd tail: only lower half-wave contributes
      int da = nbkt[l][j];
      float4 wa = lds_w[ws][j];
      float4 xa = xq[(size_t)da * 32 + fl];
      if (half == 0) {
        A0.x = fmaf(wa.x, xa.x, A0.x); A0.y = fmaf(wa.x, xa.y, A0.y);
        A0.z = fmaf(wa.x, xa.z, A0.z); A0.w = fmaf(wa.x, xa.w, A0.w);
        A1.x = fmaf(wa.y, xa.x, A1.x); A1.y = fmaf(wa.y, xa.y, A1.y);
        A1.z = fmaf(wa.y, xa.z, A1.z); A1.w = fmaf(wa.y, xa.w, A1.w);
        A2.x = fmaf(wa.z, xa.x, A2.x); A2.y = fmaf(wa.z, xa.y, A2.y);
        A2.z = fmaf(wa.z, xa.z, A2.z); A2.w = fmaf(wa.z, xa.w, A2.w);
        A3.x = fmaf(wa.w, xa.x, A3.x); A3.y = fmaf(wa.w, xa.y, A3.y);
        A3.z = fmaf(wa.w, xa.z, A3.z); A3.w = fmaf(wa.w, xa.w, A3.w);
      }
    }

    // combine the two half-waves
    A0.x += __shfl_xor(A0.x, 32, 64); A0.y += __shfl_xor(A0.y, 32, 64);
    A0.z += __shfl_xor(A0.z, 32, 64); A0.w += __shfl_xor(A0.w, 32, 64);
    A1.x += __shfl_xor(A1.x, 32, 64); A1.y += __shfl_xor(A1.y, 32, 64);
    A1.z += __shfl_xor(A1.z, 32, 64); A1.w += __shfl_xor(A1.w, 32, 64);
    A2.x += __shfl_xor(A2.x, 32, 64); A2.y += __shfl_xor(A2.y, 32, 64);
    A2.z += __shfl_xor(A2.z, 32, 64); A2.w += __shfl_xor(A2.w, 32, 64);
    A3.x += __shfl_xor(A3.x, 32, 64); A3.y += __shfl_xor(A3.y, 32, 64);
    A3.z += __shfl_xor(A3.z, 32, 64); A3.w += __shfl_xor(A3.w, 32, 64);

    float r0 = 1.f / p0, r1 = 1.f / p1, r2 = 1.f / p2, r3 = 1.f / p3;

    // round 0: heads 0 (lower half) / 1 (upper half)
    {
      float4 acc; float rr; int h;
      if (half == 0) { acc = A0; rr = r0; h = 0; } else { acc = A1; rr = r1; h = 1; }
      float4 ww = wq[h * 32 + fl];
      float4 o = {ww.x * acc.x * rr, ww.y * acc.y * rr,
                  ww.z * acc.z * rr, ww.w * acc.w * rr};
      ((float4*)out)[((size_t)h * N_NODES + n) * 32 + fl] = o;
    }
    // round 1: heads 2 / 3
    {
      float4 acc; float rr; int h;
      if (half == 0) { acc = A2; rr = r2; h = 2; } else { acc = A3; rr = r3; h = 3; }
      float4 ww = wq[h * 32 + fl];
      float4 o = {ww.x * acc.x * rr, ww.y * acc.y * rr,
                  ww.z * acc.z * rr, ww.w * acc.w * rr};
      ((float4*)out)[((size_t)h * N_NODES + n) * 32 + fl] = o;
    }
  }
}

extern "C" void kernel_launch(void* const* d_in, const int* in_sizes, int n_in,
                              void* d_out, int out_size, void* d_ws, size_t ws_size,
                              hipStream_t stream) {
  const float* x = (const float*)d_in[0];
  const float* w = (const float*)d_in[1];
  const float* a = (const float*)d_in[2];
  const int* ei = (const int*)d_in[3];
  const int* src = ei;
  const int* dst = ei + N_EDGES;
  float* out = (float*)d_out;

  char* p = (char*)d_ws;
  float4* s_src4 = (float4*)p;      p += (size_t)N_NODES * 16;
  float4* s_dst4 = (float4*)p;      p += (size_t)N_NODES * 16;
  int* gc = (int*)p;                p += 4096;
  unsigned int* region = (unsigned int*)p;
  p += (size_t)K1 * SCAP * 4;

  score_kernel<<<(N_NODES * 64 + 255) / 256, 256, 0, stream>>>(x, w, a, s_src4, s_dst4, gc);
  partition_kernel<<<P1_BLOCKS, 256, 0, stream>>>(src, dst, gc, region);
  agg_kernel<<<GROUPS, 256, 0, stream>>>(x, w, s_src4, s_dst4, gc, region, out);
}

// Round 7
// 310.583 us; speedup vs baseline: 1.0724x; 1.0724x over previous
//
#include <hip/hip_runtime.h>

#define N_NODES 50000
#define N_EDGES 1600000
#define N_HEAD 4
#define F_OUT 128
#define CAP 96        // per-node bucket capacity; Poisson(32), P(>96) ~ 5e-14
#define NPS 512       // nodes per super-bucket
#define K1 98         // ceil(50000/512)
#define SCAP 17408    // super capacity: mean 16327 + ~8.5 sigma
#define NPG 16        // nodes per agg group
#define GROUPS 3125   // 50000/16
#define GPS 32        // groups per super (512/16)
#define EPB 4096      // edges per partition block
#define P1_BLOCKS ((N_EDGES + EPB - 1) / EPB)   // 391

// ---------------- K1: per-node scores + gc zeroing ------------------------------
__global__ void __launch_bounds__(256) score_kernel(
    const float* __restrict__ x, const float* __restrict__ w,
    const float* __restrict__ a, float4* __restrict__ s_src4,
    float4* __restrict__ s_dst4, int* __restrict__ gc) {
  if (blockIdx.x == 0 && threadIdx.x < K1) gc[threadIdx.x] = 0;
  int wv = (blockIdx.x * blockDim.x + threadIdx.x) >> 6;
  int lane = threadIdx.x & 63;
  if (wv >= N_NODES) return;
  float xv0 = x[wv * F_OUT + lane];
  float xv1 = x[wv * F_OUT + 64 + lane];
  float ps[N_HEAD], pd[N_HEAD];
#pragma unroll
  for (int h = 0; h < N_HEAD; ++h) {
    float w0 = w[h * F_OUT + lane];
    float w1 = w[h * F_OUT + 64 + lane];
    float as0 = a[h * 2 * F_OUT + lane];
    float as1 = a[h * 2 * F_OUT + 64 + lane];
    float ad0 = a[h * 2 * F_OUT + F_OUT + lane];
    float ad1 = a[h * 2 * F_OUT + F_OUT + 64 + lane];
    ps[h] = xv0 * w0 * as0 + xv1 * w1 * as1;
    pd[h] = xv0 * w0 * ad0 + xv1 * w1 * ad1;
  }
#pragma unroll
  for (int off = 32; off > 0; off >>= 1) {
#pragma unroll
    for (int h = 0; h < N_HEAD; ++h) {
      ps[h] += __shfl_xor(ps[h], off, 64);
      pd[h] += __shfl_xor(pd[h], off, 64);
    }
  }
  if (lane == 0) {
    s_src4[wv] = make_float4(ps[0], ps[1], ps[2], ps[3]);
    s_dst4[wv] = make_float4(pd[0], pd[1], pd[2], pd[3]);
  }
}

// ---------------- K2: block-local counting sort -> coalesced run writes ---------
__global__ void __launch_bounds__(256) partition_kernel(
    const int* __restrict__ src, const int* __restrict__ dst,
    int* __restrict__ gc, unsigned int* __restrict__ region) {
  __shared__ int hist[K1], cur[K1], lstart[K1], gpos[K1];
  __shared__ unsigned int staging[EPB];
  const int tid = threadIdx.x;
  const int base = blockIdx.x * EPB;
  int vc = N_EDGES - base;
  if (vc > EPB) vc = EPB;

  unsigned int pk[EPB / 256];
#pragma unroll
  for (int k = 0; k < EPB / 256; ++k) {
    int i = k * 256 + tid;
    if (i < vc) {
      unsigned int s = (unsigned int)src[base + i];
      unsigned int d = (unsigned int)dst[base + i];
      pk[k] = (s << 16) | d;
    } else {
      pk[k] = 0xffffffffu;
    }
  }
  if (tid < K1) { hist[tid] = 0; cur[tid] = 0; }
  __syncthreads();
#pragma unroll
  for (int k = 0; k < EPB / 256; ++k)
    if (pk[k] != 0xffffffffu) atomicAdd(&hist[pk[k] >> 25], 1);
  __syncthreads();
  if (tid < 64) {
    int carry = 0;
    for (int b0 = 0; b0 < K1; b0 += 64) {
      int idx = b0 + tid;
      int h = (idx < K1) ? hist[idx] : 0;
      int v = h;
#pragma unroll
      for (int off = 1; off < 64; off <<= 1) {
        int t = __shfl_up(v, off, 64);
        if (tid >= off) v += t;
      }
      if (idx < K1) {
        lstart[idx] = carry + v - h;
        gpos[idx] = atomicAdd(&gc[idx], h);
      }
      carry += __shfl(v, 63, 64);
    }
  }
  __syncthreads();
#pragma unroll
  for (int k = 0; k < EPB / 256; ++k) {
    if (pk[k] != 0xffffffffu) {
      int b = pk[k] >> 25;
      int pos = lstart[b] + atomicAdd(&cur[b], 1);
      staging[pos] = pk[k];
    }
  }
  __syncthreads();
  for (int i = tid; i < vc; i += 256) {
    unsigned int v = staging[i];
    int b = v >> 25;
    int off = gpos[b] + (i - lstart[b]);
    if (off < SCAP) region[(size_t)b * SCAP + off] = v;
  }
}

// ---------------- K3: per-super sort by 16-node group, in-place -----------------
// One block per super. Emits exact gstart/gcnt per group so agg reads only its
// own edges (kills the 32x-redundant filter scan of R6).
__global__ void __launch_bounds__(512) group_sort_kernel(
    const int* __restrict__ gc, unsigned int* __restrict__ region,
    int* __restrict__ gstart, int* __restrict__ gcnt) {
  __shared__ unsigned int staging[SCAP];
  __shared__ int hist[GPS], start[GPS], cur[GPS];
  const int sb = blockIdx.x;
  const int tid = threadIdx.x;
  int c = gc[sb];
  if (c > SCAP) c = SCAP;
  unsigned int* reg = region + (size_t)sb * SCAP;
  if (tid < GPS) { hist[tid] = 0; cur[tid] = 0; }
  __syncthreads();
  for (int i = tid; i < c; i += 512)
    atomicAdd(&hist[(reg[i] >> 20) & (GPS - 1)], 1);
  __syncthreads();
  if (tid < GPS) {                  // 32-lane exclusive scan (wave 0)
    int h = hist[tid];
    int v = h;
#pragma unroll
    for (int off = 1; off < GPS; off <<= 1) {
      int t = __shfl_up(v, off, 64);
      if (tid >= off) v += t;
    }
    start[tid] = v - h;
    gstart[sb * GPS + tid] = sb * SCAP + (v - h);
    gcnt[sb * GPS + tid] = h;
  }
  __syncthreads();
  for (int i = tid; i < c; i += 512) {
    unsigned int v = reg[i];
    int l = (v >> 20) & (GPS - 1);
    int p = start[l] + atomicAdd(&cur[l], 1);
    staging[p] = v;
  }
  __syncthreads();
  for (int i = tid; i < c; i += 512) reg[i] = staging[i];
}

// ---------------- K4: fused LDS-bucket + gather/accumulate ----------------------
__global__ void __launch_bounds__(256, 8) agg_kernel(
    const float* __restrict__ x, const float* __restrict__ w,
    const float4* __restrict__ s_src4, const float4* __restrict__ s_dst4,
    const unsigned int* __restrict__ region, const int* __restrict__ gstart,
    const int* __restrict__ gcnt, float* __restrict__ out) {
  __shared__ int ncnt[NPG];
  __shared__ int nbkt[NPG][CAP];
  __shared__ float4 lds_w[4][CAP];
  const int tid = threadIdx.x;
  const int g = blockIdx.x;
  if (tid < NPG) ncnt[tid] = 0;
  __syncthreads();

  const int s0 = gstart[g];
  const int cnt = gcnt[g];
  for (int i = tid; i < cnt; i += 256) {
    unsigned int v = region[s0 + i];
    int l = (v >> 16) & (NPG - 1);
    int p = atomicAdd(&ncnt[l], 1);
    if (p < CAP) nbkt[l][p] = (int)(v & 0xffffu);
  }
  __syncthreads();

  const int ws = tid >> 6, lane = tid & 63;
  const int half = lane >> 5, fl = lane & 31;
  const float4* __restrict__ xq = (const float4*)x;
  const float4* __restrict__ wq = (const float4*)w;

  for (int l = ws; l < NPG; l += 4) {
    int n = g * NPG + l;
    if (n >= N_NODES) break;
    int m = ncnt[l];
    m = (m < CAP) ? m : CAP;
    float4 ss = s_src4[n];

    // ---- Phase A: weights into wave-private LDS, rowsums in registers ----
    float p0 = 0.f, p1 = 0.f, p2 = 0.f, p3 = 0.f;
    for (int j = lane; j < m; j += 64) {
      int d = nbkt[l][j];
      float4 sd = s_dst4[d];
      float sc0 = ss.x + sd.x, sc1 = ss.y + sd.y, sc2 = ss.z + sd.z, sc3 = ss.w + sd.w;
      float e0 = __expf(-fmaxf(sc0, 0.2f * sc0));
      float e1 = __expf(-fmaxf(sc1, 0.2f * sc1));
      float e2 = __expf(-fmaxf(sc2, 0.2f * sc2));
      float e3 = __expf(-fmaxf(sc3, 0.2f * sc3));
      lds_w[ws][j] = make_float4(e0, e1, e2, e3);
      p0 += e0; p1 += e1; p2 += e2; p3 += e3;
    }
#pragma unroll
    for (int off = 32; off > 0; off >>= 1) {
      p0 += __shfl_xor(p0, off, 64);
      p1 += __shfl_xor(p1, off, 64);
      p2 += __shfl_xor(p2, off, 64);
      p3 += __shfl_xor(p3, off, 64);
    }

    // ---- Phase B: half-wave per edge, float4/lane, 4 rows in flight ----
    float4 A0 = {0, 0, 0, 0}, A1 = {0, 0, 0, 0}, A2 = {0, 0, 0, 0}, A3 = {0, 0, 0, 0};
    int j = 0;
    for (; j + 3 < m; j += 4) {
      int da = nbkt[l][j + half];
      int db = nbkt[l][j + 2 + half];
      float4 wa = lds_w[ws][j + half];
      float4 wb = lds_w[ws][j + 2 + half];
      float4 xa = xq[(size_t)da * 32 + fl];
      float4 xb = xq[(size_t)db * 32 + fl];
      A0.x = fmaf(wa.x, xa.x, A0.x); A0.y = fmaf(wa.x, xa.y, A0.y);
      A0.z = fmaf(wa.x, xa.z, A0.z); A0.w = fmaf(wa.x, xa.w, A0.w);
      A1.x = fmaf(wa.y, xa.x, A1.x); A1.y = fmaf(wa.y, xa.y, A1.y);
      A1.z = fmaf(wa.y, xa.z, A1.z); A1.w = fmaf(wa.y, xa.w, A1.w);
      A2.x = fmaf(wa.z, xa.x, A2.x); A2.y = fmaf(wa.z, xa.y, A2.y);
      A2.z = fmaf(wa.z, xa.z, A2.z); A2.w = fmaf(wa.z, xa.w, A2.w);
      A3.x = fmaf(wa.w, xa.x, A3.x); A3.y = fmaf(wa.w, xa.y, A3.y);
      A3.z = fmaf(wa.w, xa.z, A3.z); A3.w = fmaf(wa.w, xa.w, A3.w);
      A0.x = fmaf(wb.x, xb.x, A0.x); A0.y = fmaf(wb.x, xb.y, A0.y);
      A0.z = fmaf(wb.x, xb.z, A0.z); A0.w = fmaf(wb.x, xb.w, A0.w);
      A1.x = fmaf(wb.y, xb.x, A1.x); A1.y = fmaf(wb.y, xb.y, A1.y);
      A1.z = fmaf(wb.y, xb.z, A1.z); A1.w = fmaf(wb.y, xb.w, A1.w);
      A2.x = fmaf(wb.z, xb.x, A2.x); A2.y = fmaf(wb.z, xb.y, A2.y);
      A2.z = fmaf(wb.z, xb.z, A2.z); A2.w = fmaf(wb.z, xb.w, A2.w);
      A3.x = fmaf(wb.w, xb.x, A3.x); A3.y = fmaf(wb.w, xb.y, A3.y);
      A3.z = fmaf(wb.w, xb.z, A3.z); A3.w = fmaf(wb.w, xb.w, A3.w);
    }
    for (; j + 1 < m; j += 2) {
      int da = nbkt[l][j + half];
      float4 wa = lds_w[ws][j + half];
      float4 xa = xq[(size_t)da * 32 + fl];
      A0.x = fmaf(wa.x, xa.x, A0.x); A0.y = fmaf(wa.x, xa.y, A0.y);
      A0.z = fmaf(wa.x, xa.z, A0.z); A0.w = fmaf(wa.x, xa.w, A0.w);
      A1.x = fmaf(wa.y, xa.x, A1.x); A1.y = fmaf(wa.y, xa.y, A1.y);
      A1.z = fmaf(wa.y, xa.z, A1.z); A1.w = fmaf(wa.y, xa.w, A1.w);
      A2.x = fmaf(wa.z, xa.x, A2.x); A2.y = fmaf(wa.z, xa.y, A2.y);
      A2.z = fmaf(wa.z, xa.z, A2.z); A2.w = fmaf(wa.z, xa.w, A2.w);
      A3.x = fmaf(wa.w, xa.x, A3.x); A3.y = fmaf(wa.w, xa.y, A3.y);
      A3.z = fmaf(wa.w, xa.z, A3.z); A3.w = fmaf(wa.w, xa.w, A3.w);
    }
    if (j < m) {
      int da = nbkt[l][j];
      float4 wa = lds_w[ws][j];
      float4 xa = xq[(size_t)da * 32 + fl];
      if (half == 0) {
        A0.x = fmaf(wa.x, xa.x, A0.x); A0.y = fmaf(wa.x, xa.y, A0.y);
        A0.z = fmaf(wa.x, xa.z, A0.z); A0.w = fmaf(wa.x, xa.w, A0.w);
        A1.x = fmaf(wa.y, xa.x, A1.x); A1.y = fmaf(wa.y, xa.y, A1.y);
        A1.z = fmaf(wa.y, xa.z, A1.z); A1.w = fmaf(wa.y, xa.w, A1.w);
        A2.x = fmaf(wa.z, xa.x, A2.x); A2.y = fmaf(wa.z, xa.y, A2.y);
        A2.z = fmaf(wa.z, xa.z, A2.z); A2.w = fmaf(wa.z, xa.w, A2.w);
        A3.x = fmaf(wa.w, xa.x, A3.x); A3.y = fmaf(wa.w, xa.y, A3.y);
        A3.z = fmaf(wa.w, xa.z, A3.z); A3.w = fmaf(wa.w, xa.w, A3.w);
      }
    }

    A0.x += __shfl_xor(A0.x, 32, 64); A0.y += __shfl_xor(A0.y, 32, 64);
    A0.z += __shfl_xor(A0.z, 32, 64); A0.w += __shfl_xor(A0.w, 32, 64);
    A1.x += __shfl_xor(A1.x, 32, 64); A1.y += __shfl_xor(A1.y, 32, 64);
    A1.z += __shfl_xor(A1.z, 32, 64); A1.w += __shfl_xor(A1.w, 32, 64);
    A2.x += __shfl_xor(A2.x, 32, 64); A2.y += __shfl_xor(A2.y, 32, 64);
    A2.z += __shfl_xor(A2.z, 32, 64); A2.w += __shfl_xor(A2.w, 32, 64);
    A3.x += __shfl_xor(A3.x, 32, 64); A3.y += __shfl_xor(A3.y, 32, 64);
    A3.z += __shfl_xor(A3.z, 32, 64); A3.w += __shfl_xor(A3.w, 32, 64);

    float r0 = 1.f / p0, r1 = 1.f / p1, r2 = 1.f / p2, r3 = 1.f / p3;
    {
      float4 acc; float rr; int h;
      if (half == 0) { acc = A0; rr = r0; h = 0; } else { acc = A1; rr = r1; h = 1; }
      float4 ww = wq[h * 32 + fl];
      float4 o = {ww.x * acc.x * rr, ww.y * acc.y * rr,
                  ww.z * acc.z * rr, ww.w * acc.w * rr};
      ((float4*)out)[((size_t)h * N_NODES + n) * 32 + fl] = o;
    }
    {
      float4 acc; float rr; int h;
      if (half == 0) { acc = A2; rr = r2; h = 2; } else { acc = A3; rr = r3; h = 3; }
      float4 ww = wq[h * 32 + fl];
      float4 o = {ww.x * acc.x * rr, ww.y * acc.y * rr,
                  ww.z * acc.z * rr, ww.w * acc.w * rr};
      ((float4*)out)[((size_t)h * N_NODES + n) * 32 + fl] = o;
    }
  }
}

extern "C" void kernel_launch(void* const* d_in, const int* in_sizes, int n_in,
                              void* d_out, int out_size, void* d_ws, size_t ws_size,
                              hipStream_t stream) {
  const float* x = (const float*)d_in[0];
  const float* w = (const float*)d_in[1];
  const float* a = (const float*)d_in[2];
  const int* ei = (const int*)d_in[3];
  const int* src = ei;
  const int* dst = ei + N_EDGES;
  float* out = (float*)d_out;

  char* p = (char*)d_ws;
  float4* s_src4 = (float4*)p;      p += (size_t)N_NODES * 16;
  float4* s_dst4 = (float4*)p;      p += (size_t)N_NODES * 16;
  int* gc = (int*)p;                p += 4096;
  int* gstart = (int*)p;            p += (size_t)K1 * GPS * 4;
  int* gcnt = (int*)p;              p += (size_t)K1 * GPS * 4;
  unsigned int* region = (unsigned int*)p;
  p += (size_t)K1 * SCAP * 4;

  score_kernel<<<(N_NODES * 64 + 255) / 256, 256, 0, stream>>>(x, w, a, s_src4, s_dst4, gc);
  partition_kernel<<<P1_BLOCKS, 256, 0, stream>>>(src, dst, gc, region);
  group_sort_kernel<<<K1, 512, 0, stream>>>(gc, region, gstart, gcnt);
  agg_kernel<<<GROUPS, 256, 0, stream>>>(x, w, s_src4, s_dst4, region, gstart, gcnt, out);
}